// Round 7
// baseline (67480.640 us; speedup 1.0000x reference)
//
#include <hip/hip_runtime.h>

// LSTM char-RNN scan: B=512, SEQ=1024, UNITS=256, NUM_CHARS=128. fp32 in/out.
// Round 6: register-resident weights + 4-WG groups with per-step h-exchange.
//   Round 6 (prev) showed per-step W re-streaming is fragile: per-wave-sliced
//   reads missed L2 20% -> 26.7 GB HBM/MALL traffic -> 10.4 ms.
//   Now: W_h (bf16, packed in MFMA B-frag order) is loaded ONCE into VGPRs:
//   each wave holds its 2 N-tiles x 8 K-tiles = 64 VGPRs for all 1024 steps.
//   N=1024 split across 4 WGs (each: 64 units x 4 gates, 8 batch rows);
//   64 groups x 4 members = 256 WGs = 256 CUs. Per step, members exchange
//   their 8x64 h-slice (hi/lo bf16 packed u32) through d_ws with device-scope
//   atomics + a group arrival counter (double-buffered by step parity).
//   Co-residency guaranteed: VGPR>128 => 8 waves/CU max => 1 WG/CU, grid=256.
// Numerics: W_h bf16 RNE; h carried as bf16 hi + bf16 residual (2 MFMAs/tile,
// effectively fp32 h); c, gates fp32. Proven absmax 4.9e-4 in rounds 5-6.

#define U       256
#define SEQ     1024
#define NC      128
#define GDIM    1024
#define ROWS    8          // batch rows per group
#define THREADS 512        // 8 waves
#define HP      264        // padded h2 row (shorts)

typedef short bf16x8 __attribute__((ext_vector_type(8)));
typedef float f32x4  __attribute__((ext_vector_type(4)));

// ---- workspace layout (bytes) ----
#define WP_OFF   0                       // 512 KB packed W
#define CTR_OFF  (512*1024)              // 16 KB counters (64 groups, 256B apart)
#define EXCH_OFF (528*1024)              // 1 MB exchange
#define EXG_STRIDE 4096                  // u32 per group: 2 par * 4 mem * 8 r * 64 u
#define WS_NEED  (EXCH_OFF + 64*EXG_STRIDE*4)

__device__ __forceinline__ float sig_(float x)  { return 1.0f / (1.0f + __expf(-x)); }
__device__ __forceinline__ float tanh_(float x) { return 1.0f - 2.0f / (__expf(2.0f * x) + 1.0f); }
__device__ __forceinline__ unsigned rne16(float f) {
    union { float f; unsigned u; } v; v.f = f;
    return (v.u + 0x7FFFu + ((v.u >> 16) & 1u)) >> 16;
}
__device__ __forceinline__ float u2f(unsigned u) {
    union { unsigned u; float f; } v; v.u = u; return v.f;
}

// ---- pack W_h into member-sliced MFMA B-frag order ----
// Wp idx = ((s*16 + nt)*8 + kt)*64 + lane   (uint4)
// member s owns units [s*64, s*64+64); slice col c = gate*64 + u_local,
// nt = c>>4; global col = gate*256 + s*64 + (nt&3)*16 + (lane&15);
// k = kt*32 + (lane>>4)*8 + 2d(+1) per dword d.
__global__ __launch_bounds__(256)
void pack_wh(const float* __restrict__ Wh, uint4* __restrict__ Wp) {
    int i    = blockIdx.x * 256 + threadIdx.x;   // [0, 32768)
    int lane = i & 63;
    int kt   = (i >> 6) & 7;
    int nt   = (i >> 9) & 15;
    int s    = i >> 13;
    int gate = nt >> 2;
    int col  = gate * 256 + s * 64 + (nt & 3) * 16 + (lane & 15);
    int k0   = kt * 32 + ((lane >> 4) * 8);
    const float* base = Wh + (size_t)k0 * GDIM + col;
    unsigned p0 = rne16(base[0 * GDIM]) | (rne16(base[1 * GDIM]) << 16);
    unsigned p1 = rne16(base[2 * GDIM]) | (rne16(base[3 * GDIM]) << 16);
    unsigned p2 = rne16(base[4 * GDIM]) | (rne16(base[5 * GDIM]) << 16);
    unsigned p3 = rne16(base[6 * GDIM]) | (rne16(base[7 * GDIM]) << 16);
    Wp[i] = make_uint4(p0, p1, p2, p3);
}

__global__ __launch_bounds__(256)
void init_sync(unsigned* __restrict__ ctr) {
    ctr[blockIdx.x * 256 + threadIdx.x] = 0u;    // zero 4096 u32 (16 KB)
}

__global__ __launch_bounds__(THREADS, 2)
void lstm_grp(const int* __restrict__ tokens,
              const float* __restrict__ Wx,     // [128,1024]
              const float* __restrict__ bias,   // [1024]
              const float* __restrict__ Wd,     // [256,128]
              const float* __restrict__ bd,     // [128]
              const uint4* __restrict__ Wp,     // packed W (ws)
              unsigned* __restrict__ ctr,       // group counters (ws)
              unsigned* __restrict__ exch,      // h exchange (ws)
              float* __restrict__ out)          // [512,128]
{
    __shared__ short h2hi[16][HP];    // 8.25 KB (rows 8..15 stay zero)
    __shared__ short h2lo[16][HP];    // 8.25 KB
    __shared__ float G[ROWS][U];      // 8 KB   gates [row][gate*64+u]
    __shared__ int   tokw[ROWS][128]; // 4 KB   128-step token window

    const int b    = blockIdx.x;
    const int m    = (b >> 3) & 3;               // member 0..3 (stride-8 blocks)
    const int g    = (b & 7) * 8 + (b >> 5);     // group 0..63 (same-XCD heuristic)
    const int r0   = g * ROWS;
    const int tid  = threadIdx.x;
    const int lane = tid & 63;
    const int w    = tid >> 6;                   // wave 0..7
    const int mrow = lane & 15;
    const int quad = lane >> 4;
    const int uu   = tid & 63;                   // update unit (local)
    const int ur   = tid >> 6;                   // update row 0..7
    const int ug   = m * 64 + uu;                // update unit (global)

    // ---- persistent B fragments: wave w owns nt = 2w, 2w+1 (64 VGPRs) ----
    bf16x8 Bfr[2][8];
    {
        const uint4* base = Wp + ((size_t)(m * 16 + 2 * w) * 8) * 64 + lane;
        #pragma unroll
        for (int n2 = 0; n2 < 2; ++n2)
            #pragma unroll
            for (int kt = 0; kt < 8; ++kt) {
                union { uint4 u; bf16x8 v; } t;
                t.u = base[(n2 * 8 + kt) * 64];
                Bfr[n2][kt] = t.v;
            }
    }

    for (int i = tid; i < 16 * HP; i += THREADS) {
        ((short*)h2hi)[i] = 0;
        ((short*)h2lo)[i] = 0;
    }
    for (int i = tid; i < ROWS * 128; i += THREADS)
        ((int*)tokw)[i] = tokens[(r0 + (i >> 7)) * SEQ + (i & 127)];

    const float b_i = bias[ug];
    const float b_j = bias[256 + ug];
    const float b_f = bias[512 + ug] + 1.0f;     // forget_bias folded
    const float b_o = bias[768 + ug];
    float cst = 0.0f;

    unsigned* exg  = exch + (size_t)g * EXG_STRIDE;
    unsigned* ctrg = ctr + g * 64;

    const short* ah = &h2hi[mrow][quad * 8];
    const short* al = &h2lo[mrow][quad * 8];

    __syncthreads();

    for (int t = 0; t < SEQ; ++t) {
        // token + Wx gather issued early (consumed after GEMM barrier)
        const int xr = tokw[ur][t & 127];
        const float* wxp = Wx + (size_t)xr * GDIM + ug;
        const float wxi = wxp[0], wxj = wxp[256], wxf = wxp[512], wxo = wxp[768];

        // A-fragments (hi + lo) for all 8 K-tiles
        bf16x8 Ah[8], Al[8];
        #pragma unroll
        for (int kt = 0; kt < 8; ++kt) {
            Ah[kt] = *(const bf16x8*)(ah + kt * 32);
            Al[kt] = *(const bf16x8*)(al + kt * 32);
        }

        // GEMM: 2 N-tiles per wave, W from registers
        #pragma unroll
        for (int n2 = 0; n2 < 2; ++n2) {
            f32x4 acc = {0.f, 0.f, 0.f, 0.f};
            #pragma unroll
            for (int kt = 0; kt < 8; ++kt) {
                acc = __builtin_amdgcn_mfma_f32_16x16x32_bf16(Ah[kt], Bfr[n2][kt], acc, 0, 0, 0);
                acc = __builtin_amdgcn_mfma_f32_16x16x32_bf16(Al[kt], Bfr[n2][kt], acc, 0, 0, 0);
            }
            if (quad < 2) {                       // rows 0..7 real
                const int c = (2 * w + n2) * 16 + mrow;
                #pragma unroll
                for (int rr = 0; rr < 4; ++rr)
                    G[quad * 4 + rr][c] = acc[rr];
            }
        }
        __syncthreads();

        // LSTM update for cell (ur, ug). Gate order i, j, f, o.
        float gi = G[ur][uu]        + wxi + b_i;
        float gj = G[ur][64 + uu]   + wxj + b_j;
        float gf = G[ur][128 + uu]  + wxf + b_f;
        float go = G[ur][192 + uu]  + wxo + b_o;
        cst = cst * sig_(gf) + sig_(gi) * tanh_(gj);
        float nh = tanh_(cst) * sig_(go);
        unsigned hi = rne16(nh);
        float lo = nh - u2f(hi << 16);
        unsigned pk = (hi << 16) | rne16(lo);

        const int par = t & 1;
        unsigned* slot = exg + par * 2048 + m * 512 + ur * 64 + uu;
        __hip_atomic_store(slot, pk, __ATOMIC_RELAXED, __HIP_MEMORY_SCOPE_AGENT);
        __threadfence();                          // release our stores (agent)
        __syncthreads();
        if (tid == 0)
            __hip_atomic_fetch_add(ctrg, 1u, __ATOMIC_RELEASE, __HIP_MEMORY_SCOPE_AGENT);

        // own slice into LDS while waiting
        h2hi[ur][m * 64 + uu] = (short)(pk >> 16);
        h2lo[ur][m * 64 + uu] = (short)(pk & 0xffffu);

        if (tid == 0) {
            const unsigned tgt = 4u * (unsigned)(t + 1);
            while (__hip_atomic_load(ctrg, __ATOMIC_ACQUIRE, __HIP_MEMORY_SCOPE_AGENT) < tgt)
                __builtin_amdgcn_s_sleep(1);
        }
        __syncthreads();
        __threadfence();                          // acquire before sibling reads

        #pragma unroll
        for (int d = 1; d < 4; ++d) {
            const int mm = (m + d) & 3;
            unsigned v = __hip_atomic_load(exg + par * 2048 + mm * 512 + ur * 64 + uu,
                                           __ATOMIC_RELAXED, __HIP_MEMORY_SCOPE_AGENT);
            h2hi[ur][mm * 64 + uu] = (short)(v >> 16);
            h2lo[ur][mm * 64 + uu] = (short)(v & 0xffffu);
        }
        __syncthreads();

        if (((t + 1) & 127) == 0 && (t + 1) < SEQ) {   // reload token window
            const int t0 = t + 1;
            for (int i = tid; i < ROWS * 128; i += THREADS)
                ((int*)tokw)[i] = tokens[(r0 + (i >> 7)) * SEQ + t0 + (i & 127)];
            __syncthreads();
        }
    }

    // final dense: member 0 of each group writes its 8 rows
    if (m == 0) {
        for (int o = tid; o < ROWS * NC; o += THREADS) {
            const int r = o >> 7;
            const int n = o & (NC - 1);
            float sum = bd[n];
            #pragma unroll 4
            for (int k = 0; k < U; ++k) {
                float hk = u2f(((unsigned)(unsigned short)h2hi[r][k]) << 16)
                         + u2f(((unsigned)(unsigned short)h2lo[r][k]) << 16);
                sum = fmaf(hk, Wd[k * NC + n], sum);
            }
            out[(r0 + r) * NC + n] = sum;
        }
    }
}

// ================= fallback: round-5 streaming kernel (proven 7.6 ms) =========
__global__ __launch_bounds__(256)
void pack_kq(const float* __restrict__ Wh, uint4* __restrict__ Whb) {
    int idx = blockIdx.x * 256 + threadIdx.x;   // [0, 32768)
    int kq  = idx >> 10;
    int c   = idx & 1023;
    const float* base = Wh + (size_t)(kq * 8) * GDIM + c;
    unsigned p0 = rne16(base[0 * GDIM]) | (rne16(base[1 * GDIM]) << 16);
    unsigned p1 = rne16(base[2 * GDIM]) | (rne16(base[3 * GDIM]) << 16);
    unsigned p2 = rne16(base[4 * GDIM]) | (rne16(base[5 * GDIM]) << 16);
    unsigned p3 = rne16(base[6 * GDIM]) | (rne16(base[7 * GDIM]) << 16);
    Whb[idx] = make_uint4(p0, p1, p2, p3);
}

__global__ __launch_bounds__(1024, 4)
void lstm_stream(const int* __restrict__ tokens,
                 const float* __restrict__ Wx,
                 const uint4* __restrict__ Whb,
                 const float* __restrict__ bias,
                 const float* __restrict__ Wd,
                 const float* __restrict__ bd,
                 float* __restrict__ out)
{
    __shared__ float h32[2][U];
    __shared__ float G2[GDIM][2];
    __shared__ int   tok[2][SEQ];

    const int tid = threadIdx.x;
    const int r0  = blockIdx.x * 2;

    for (int i = tid; i < 2 * SEQ; i += 1024)
        ((int*)tok)[i] = tokens[r0 * SEQ + i];
    if (tid < 2 * U) ((float*)h32)[tid] = 0.0f;

    const float b_c = bias[tid];
    float c_state = 0.0f;
    const int ur = tid >> 8;
    const int uu = tid & 255;
    __syncthreads();

    const uint4* wp = Whb + tid;
    for (int t = 0; t < SEQ; ++t) {
        const int x0 = tok[0][t];
        const int x1 = tok[1][t];
        float a0e = Wx[x0 * GDIM + tid] + b_c;
        float a1e = Wx[x1 * GDIM + tid] + b_c;
        float a0o = 0.f, a1o = 0.f;
        #pragma unroll 4
        for (int kq = 0; kq < 32; ++kq) {
            float4 h0a = *(const float4*)&h32[0][kq * 8];
            float4 h0b = *(const float4*)&h32[0][kq * 8 + 4];
            float4 h1a = *(const float4*)&h32[1][kq * 8];
            float4 h1b = *(const float4*)&h32[1][kq * 8 + 4];
            uint4 wv = wp[kq << 10];
            float we0 = u2f(wv.x << 16), wo0 = u2f(wv.x & 0xffff0000u);
            float we1 = u2f(wv.y << 16), wo1 = u2f(wv.y & 0xffff0000u);
            float we2 = u2f(wv.z << 16), wo2 = u2f(wv.z & 0xffff0000u);
            float we3 = u2f(wv.w << 16), wo3 = u2f(wv.w & 0xffff0000u);
            a0e = fmaf(h0a.x, we0, a0e); a0o = fmaf(h0a.y, wo0, a0o);
            a1e = fmaf(h1a.x, we0, a1e); a1o = fmaf(h1a.y, wo0, a1o);
            a0e = fmaf(h0a.z, we1, a0e); a0o = fmaf(h0a.w, wo1, a0o);
            a1e = fmaf(h1a.z, we1, a1e); a1o = fmaf(h1a.w, wo1, a1o);
            a0e = fmaf(h0b.x, we2, a0e); a0o = fmaf(h0b.y, wo2, a0o);
            a1e = fmaf(h1b.x, we2, a1e); a1o = fmaf(h1b.y, wo2, a1o);
            a0e = fmaf(h0b.z, we3, a0e); a0o = fmaf(h0b.w, wo3, a0o);
            a1e = fmaf(h1b.z, we3, a1e); a1o = fmaf(h1b.w, wo3, a1o);
        }
        *(float2*)&G2[tid][0] = make_float2(a0e + a0o, a1e + a1o);
        __syncthreads();
        if (tid < 2 * U) {
            float gi = G2[uu][ur];
            float gj = G2[U + uu][ur];
            float gf = G2[2 * U + uu][ur];
            float go = G2[3 * U + uu][ur];
            c_state = c_state * sig_(gf + 1.0f) + sig_(gi) * tanh_(gj);
            h32[ur][uu] = tanh_(c_state) * sig_(go);
        }
        __syncthreads();
    }
    if (tid < 2 * NC) {
        const int r = tid >> 7;
        const int n = tid & (NC - 1);
        float sum = bd[n];
        #pragma unroll 4
        for (int k = 0; k < U; ++k)
            sum = fmaf(h32[r][k], Wd[k * NC + n], sum);
        out[(r0 + r) * NC + n] = sum;
    }
}

extern "C" void kernel_launch(void* const* d_in, const int* in_sizes, int n_in,
                              void* d_out, int out_size, void* d_ws, size_t ws_size,
                              hipStream_t stream) {
    const int*   tokens = (const int*)d_in[0];
    const float* Wx     = (const float*)d_in[1];
    const float* Wh     = (const float*)d_in[2];
    const float* bias   = (const float*)d_in[3];
    const float* Wd     = (const float*)d_in[4];
    const float* bd     = (const float*)d_in[5];
    float*       out    = (float*)d_out;

    if (ws_size >= (size_t)WS_NEED) {
        uint4*    Wp = (uint4*)((char*)d_ws + WP_OFF);
        unsigned* ct = (unsigned*)((char*)d_ws + CTR_OFF);
        unsigned* ex = (unsigned*)((char*)d_ws + EXCH_OFF);
        pack_wh<<<128, 256, 0, stream>>>(Wh, Wp);
        init_sync<<<16, 256, 0, stream>>>(ct);
        lstm_grp<<<256, THREADS, 0, stream>>>(tokens, Wx, bias, Wd, bd, Wp, ct, ex, out);
    } else {
        uint4* Whb = (uint4*)d_ws;                 // 512 KB (proven available)
        pack_kq<<<128, 256, 0, stream>>>(Wh, Whb);
        lstm_stream<<<256, 1024, 0, stream>>>(tokens, Wx, Whb, bias, Wd, bd, out);
    }
}

// Round 8
// 5948.517 us; speedup vs baseline: 11.3441x; 11.3441x over previous
//
#include <hip/hip_runtime.h>

// LSTM char-RNN scan: B=512, SEQ=1024, UNITS=256, NUM_CHARS=128. fp32 in/out.
// Round 7: CU-resident weights, zero cross-WG communication (round-7 lesson:
// per-step cross-WG sync on non-coherent XCD L2s costs ~66 us/step — dead).
//   - BC=16 rows/WG (full MFMA M-tile), 32 WGs.
//   - W_h (bf16, MFMA B-frag order): 256 KB in VGPRs (8 waves x 32 KB),
//     128 KB in LDS, 128 KB/step streamed from L2 (vs 512 KB in round 5).
//   - Wave w owns N-tiles {w,16+w,32+w,48+w} + {8+w,...}: its accumulators are
//     gates i,j,f,o of units w*16.. and (8+w)*16.. -> LSTM update fully
//     in-register, no gate LDS round-trip.
//   - h as hi/lo bf16 pair in MFMA-A-swizzled LDS (effectively fp32; proven
//     absmax 4.9e-4 in rounds 3-6). Wx+bias pre-packed float4 per (x,unit).
// Budget/step/CU: LDS 384 KB ~3k cyc (binder), stream 128 KB ~2.1k, MFMA 1.24k.

#define U       256
#define SEQ     1024
#define NC      128
#define GDIM    1024
#define BCR     16         // batch rows per WG
#define THREADS 512        // 8 waves

typedef short bf16x8 __attribute__((ext_vector_type(8)));
typedef float f32x4  __attribute__((ext_vector_type(4)));

#define WP_OFF   0                        // 512 KB packed W_h
#define WXP_OFF  (512*1024)               // 512 KB packed Wx+bias
#define WS_NEED  (1024*1024)

__device__ __forceinline__ float sig_(float x)  { return 1.0f / (1.0f + __expf(-x)); }
__device__ __forceinline__ float tanh_(float x) { return 1.0f - 2.0f / (__expf(2.0f * x) + 1.0f); }
__device__ __forceinline__ unsigned rne16(float f) {
    union { float f; unsigned u; } v; v.f = f;
    return (v.u + 0x7FFFu + ((v.u >> 16) & 1u)) >> 16;
}
__device__ __forceinline__ float u2f(unsigned u) {
    union { unsigned u; float f; } v; v.u = u; return v.f;
}

// ---- pack W_h into MFMA B-frag order (validated in rounds 5/6) ----
// Wp[(nt*8+kt)*64 + lane]: col = nt*16+(lane&15); k = kt*32+(lane>>4)*8 + j,
// dword d packs (k=2d lo, k=2d+1 hi).
__global__ __launch_bounds__(256)
void pack_wh(const float* __restrict__ Wh, uint4* __restrict__ Wp) {
    int i    = blockIdx.x * 256 + threadIdx.x;   // [0, 32768)
    int lane = i & 63;
    int kt   = (i >> 6) & 7;
    int nt   = i >> 9;
    int col  = nt * 16 + (lane & 15);
    int k0   = kt * 32 + ((lane >> 4) * 8);
    const float* base = Wh + (size_t)k0 * GDIM + col;
    unsigned p0 = rne16(base[0 * GDIM]) | (rne16(base[1 * GDIM]) << 16);
    unsigned p1 = rne16(base[2 * GDIM]) | (rne16(base[3 * GDIM]) << 16);
    unsigned p2 = rne16(base[4 * GDIM]) | (rne16(base[5 * GDIM]) << 16);
    unsigned p3 = rne16(base[6 * GDIM]) | (rne16(base[7 * GDIM]) << 16);
    Wp[i] = make_uint4(p0, p1, p2, p3);
}

// ---- pack Wx + bias (+forget_bias) into float4 per (x, unit) ----
__global__ __launch_bounds__(256)
void pack_wx(const float* __restrict__ Wx, const float* __restrict__ bias,
             float4* __restrict__ Wxp) {
    int i = blockIdx.x * 256 + threadIdx.x;      // [0, 32768)
    int x = i >> 8, u = i & 255;
    const float* r = Wx + (size_t)x * GDIM;
    Wxp[i] = make_float4(r[u]       + bias[u],
                         r[256 + u] + bias[256 + u],
                         r[512 + u] + bias[512 + u] + 1.0f,   // forget_bias
                         r[768 + u] + bias[768 + u]);
}

__global__ __launch_bounds__(THREADS, 2)
void lstm_reg(const int* __restrict__ tokens,
              const uint4* __restrict__ Wp,     // packed W_h (ws)
              const float4* __restrict__ Wxp,   // packed Wx+b (ws)
              const float* __restrict__ Wd,     // [256,128]
              const float* __restrict__ bd,     // [128]
              float* __restrict__ out)          // [512,128]
{
    __shared__ uint4 LW[16][8][64];   // 128 KB  W in LDS (per wave: 2 nt)
    __shared__ short AH[8][64][8];    // 8 KB    h hi, MFMA-A swizzled
    __shared__ short AL[8][64][8];    // 8 KB    h lo residual

    const int tid  = threadIdx.x;
    const int wv   = tid >> 6;        // wave 0..7
    const int lane = tid & 63;
    const int m    = lane & 15;
    const int quad = lane >> 4;
    const int r0   = blockIdx.x * BCR;

    // N-tile ownership (gate g of unit u lives at nt = g*16 + (u>>4)):
    //   block A units (wv)*16+m  : gates at nt {wv, 16+wv, 32+wv, 48+wv}
    //   block B units (8+wv)*16+m: gates at nt {8+wv, 24+wv, 40+wv, 56+wv}
    // Storage: REG = {A-i, A-j, B-i, B-j}; LDS = {A-f, B-f}; STREAM = {A-o, B-o}.
    bf16x8 WR[4][8];
    {
        const int ntR[4] = {wv, 16 + wv, 8 + wv, 24 + wv};
        #pragma unroll
        for (int jj = 0; jj < 4; ++jj)
            #pragma unroll
            for (int kt = 0; kt < 8; ++kt) {
                union { uint4 u; bf16x8 v; } c;
                c.u = Wp[((size_t)(ntR[jj] * 8 + kt)) * 64 + lane];
                WR[jj][kt] = c.v;
            }
    }
    #pragma unroll
    for (int li = 0; li < 2; ++li) {
        const int nt = 32 + wv + li * 8;          // A-f, B-f
        #pragma unroll
        for (int kt = 0; kt < 8; ++kt)
            LW[wv * 2 + li][kt][lane] = Wp[((size_t)(nt * 8 + kt)) * 64 + lane];
    }
    for (int i = tid; i < 2048; i += THREADS) {   // zero h (8 KB each as ints)
        ((int*)AH)[i] = 0;
        ((int*)AL)[i] = 0;
    }

    float cst[2][4] = {{0.f, 0.f, 0.f, 0.f}, {0.f, 0.f, 0.f, 0.f}};
    const uint4* wsA = Wp + ((size_t)(48 + wv) * 8) * 64 + lane;   // stream A-o
    const uint4* wsB = Wp + ((size_t)(56 + wv) * 8) * 64 + lane;   // stream B-o

    __syncthreads();

    for (int t = 0; t < SEQ; ++t) {
        // ---- MFMA phase: 8 nt x 8 kt x (hi+lo) ----
        f32x4 acc[8];
        #pragma unroll
        for (int j = 0; j < 8; ++j) acc[j] = (f32x4){0.f, 0.f, 0.f, 0.f};

        uint4 s3 = wsA[0], s7 = wsB[0];           // prefetch kt=0 streamed tiles
        #pragma unroll
        for (int kt = 0; kt < 8; ++kt) {
            bf16x8 ah = *(const bf16x8*)&AH[kt][lane][0];
            bf16x8 al = *(const bf16x8*)&AL[kt][lane][0];
            uint4 n3, n7;
            if (kt < 7) { n3 = wsA[(kt + 1) * 64]; n7 = wsB[(kt + 1) * 64]; }
            union { uint4 u; bf16x8 v; } b3, b7, l2, l6;
            b3.u = s3; b7.u = s7;
            l2.u = LW[wv * 2 + 0][kt][lane];
            l6.u = LW[wv * 2 + 1][kt][lane];
            acc[0] = __builtin_amdgcn_mfma_f32_16x16x32_bf16(ah, WR[0][kt], acc[0], 0, 0, 0);
            acc[0] = __builtin_amdgcn_mfma_f32_16x16x32_bf16(al, WR[0][kt], acc[0], 0, 0, 0);
            acc[1] = __builtin_amdgcn_mfma_f32_16x16x32_bf16(ah, WR[1][kt], acc[1], 0, 0, 0);
            acc[1] = __builtin_amdgcn_mfma_f32_16x16x32_bf16(al, WR[1][kt], acc[1], 0, 0, 0);
            acc[2] = __builtin_amdgcn_mfma_f32_16x16x32_bf16(ah, l2.v, acc[2], 0, 0, 0);
            acc[2] = __builtin_amdgcn_mfma_f32_16x16x32_bf16(al, l2.v, acc[2], 0, 0, 0);
            acc[3] = __builtin_amdgcn_mfma_f32_16x16x32_bf16(ah, b3.v, acc[3], 0, 0, 0);
            acc[3] = __builtin_amdgcn_mfma_f32_16x16x32_bf16(al, b3.v, acc[3], 0, 0, 0);
            acc[4] = __builtin_amdgcn_mfma_f32_16x16x32_bf16(ah, WR[2][kt], acc[4], 0, 0, 0);
            acc[4] = __builtin_amdgcn_mfma_f32_16x16x32_bf16(al, WR[2][kt], acc[4], 0, 0, 0);
            acc[5] = __builtin_amdgcn_mfma_f32_16x16x32_bf16(ah, WR[3][kt], acc[5], 0, 0, 0);
            acc[5] = __builtin_amdgcn_mfma_f32_16x16x32_bf16(al, WR[3][kt], acc[5], 0, 0, 0);
            acc[6] = __builtin_amdgcn_mfma_f32_16x16x32_bf16(ah, l6.v, acc[6], 0, 0, 0);
            acc[6] = __builtin_amdgcn_mfma_f32_16x16x32_bf16(al, l6.v, acc[6], 0, 0, 0);
            acc[7] = __builtin_amdgcn_mfma_f32_16x16x32_bf16(ah, b7.v, acc[7], 0, 0, 0);
            acc[7] = __builtin_amdgcn_mfma_f32_16x16x32_bf16(al, b7.v, acc[7], 0, 0, 0);
            s3 = n3; s7 = n7;
        }

        // ---- in-register LSTM update: 2 unit-blocks x 4 rows per lane ----
        unsigned hh[2][4], hl[2][4];
        #pragma unroll
        for (int blk = 0; blk < 2; ++blk) {
            const int u = (wv + 8 * blk) * 16 + m;
            #pragma unroll
            for (int ri = 0; ri < 4; ++ri) {
                const int row = quad * 4 + ri;
                const int x = tokens[(size_t)(r0 + row) * SEQ + t];
                float4 wx = Wxp[(size_t)x * 256 + u];
                float gi = acc[blk * 4 + 0][ri] + wx.x;
                float gj = acc[blk * 4 + 1][ri] + wx.y;
                float gf = acc[blk * 4 + 2][ri] + wx.z;   // forget_bias folded
                float go = acc[blk * 4 + 3][ri] + wx.w;
                float c  = cst[blk][ri];
                c = c * sig_(gf) + sig_(gi) * tanh_(gj);
                cst[blk][ri] = c;
                float nh = tanh_(c) * sig_(go);
                unsigned hi = rne16(nh);
                hh[blk][ri] = hi;
                hl[blk][ri] = rne16(nh - u2f(hi << 16));
            }
        }
        __syncthreads();       // all A-reads of this step complete

        #pragma unroll
        for (int blk = 0; blk < 2; ++blk) {
            const int u = (wv + 8 * blk) * 16 + m;
            const int kt_u = u >> 5, qa = (u >> 3) & 3, ju = u & 7;
            #pragma unroll
            for (int ri = 0; ri < 4; ++ri) {
                const int row = quad * 4 + ri;
                const int idx = ((kt_u * 64 + qa * 16 + row) << 3) + ju;
                ((short*)AH)[idx] = (short)hh[blk][ri];
                ((short*)AL)[idx] = (short)hl[blk][ri];
            }
        }
        __syncthreads();       // new h visible
    }

    // ---- final dense ----
    for (int o = tid; o < BCR * NC; o += THREADS) {
        const int r = o >> 7;
        const int n = o & (NC - 1);
        float sum = bd[n];
        #pragma unroll 4
        for (int k = 0; k < U; ++k) {
            const int idx = (((k >> 5) * 64 + ((k >> 3) & 3) * 16 + r) << 3) + (k & 7);
            float hk = u2f(((unsigned)(unsigned short)((short*)AH)[idx]) << 16)
                     + u2f(((unsigned)(unsigned short)((short*)AL)[idx]) << 16);
            sum = fmaf(hk, Wd[k * NC + n], sum);
        }
        out[(size_t)(r0 + r) * NC + n] = sum;
    }
}

// ================= fallback: round-5 streaming kernel (proven 7.6 ms) =========
__global__ __launch_bounds__(256)
void pack_kq(const float* __restrict__ Wh, uint4* __restrict__ Whb) {
    int idx = blockIdx.x * 256 + threadIdx.x;
    int kq  = idx >> 10;
    int c   = idx & 1023;
    const float* base = Wh + (size_t)(kq * 8) * GDIM + c;
    unsigned p0 = rne16(base[0 * GDIM]) | (rne16(base[1 * GDIM]) << 16);
    unsigned p1 = rne16(base[2 * GDIM]) | (rne16(base[3 * GDIM]) << 16);
    unsigned p2 = rne16(base[4 * GDIM]) | (rne16(base[5 * GDIM]) << 16);
    unsigned p3 = rne16(base[6 * GDIM]) | (rne16(base[7 * GDIM]) << 16);
    Whb[idx] = make_uint4(p0, p1, p2, p3);
}

__global__ __launch_bounds__(1024, 4)
void lstm_stream(const int* __restrict__ tokens, const float* __restrict__ Wx,
                 const uint4* __restrict__ Whb, const float* __restrict__ bias,
                 const float* __restrict__ Wd, const float* __restrict__ bd,
                 float* __restrict__ out)
{
    __shared__ float h32[2][U];
    __shared__ float G2[GDIM][2];
    __shared__ int   tok[2][SEQ];
    const int tid = threadIdx.x;
    const int r0  = blockIdx.x * 2;
    for (int i = tid; i < 2 * SEQ; i += 1024)
        ((int*)tok)[i] = tokens[r0 * SEQ + i];
    if (tid < 2 * U) ((float*)h32)[tid] = 0.0f;
    const float b_c = bias[tid];
    float c_state = 0.0f;
    const int ur = tid >> 8, uu = tid & 255;
    __syncthreads();
    const uint4* wp = Whb + tid;
    for (int t = 0; t < SEQ; ++t) {
        const int x0 = tok[0][t], x1 = tok[1][t];
        float a0e = Wx[x0 * GDIM + tid] + b_c;
        float a1e = Wx[x1 * GDIM + tid] + b_c;
        float a0o = 0.f, a1o = 0.f;
        #pragma unroll 4
        for (int kq = 0; kq < 32; ++kq) {
            float4 h0a = *(const float4*)&h32[0][kq * 8];
            float4 h0b = *(const float4*)&h32[0][kq * 8 + 4];
            float4 h1a = *(const float4*)&h32[1][kq * 8];
            float4 h1b = *(const float4*)&h32[1][kq * 8 + 4];
            uint4 wv2 = wp[kq << 10];
            float we0 = u2f(wv2.x << 16), wo0 = u2f(wv2.x & 0xffff0000u);
            float we1 = u2f(wv2.y << 16), wo1 = u2f(wv2.y & 0xffff0000u);
            float we2 = u2f(wv2.z << 16), wo2 = u2f(wv2.z & 0xffff0000u);
            float we3 = u2f(wv2.w << 16), wo3 = u2f(wv2.w & 0xffff0000u);
            a0e = fmaf(h0a.x, we0, a0e); a0o = fmaf(h0a.y, wo0, a0o);
            a1e = fmaf(h1a.x, we0, a1e); a1o = fmaf(h1a.y, wo0, a1o);
            a0e = fmaf(h0a.z, we1, a0e); a0o = fmaf(h0a.w, wo1, a0o);
            a1e = fmaf(h1a.z, we1, a1e); a1o = fmaf(h1a.w, wo1, a1o);
            a0e = fmaf(h0b.x, we2, a0e); a0o = fmaf(h0b.y, wo2, a0o);
            a1e = fmaf(h1b.x, we2, a1e); a1o = fmaf(h1b.y, wo2, a1o);
            a0e = fmaf(h0b.z, we3, a0e); a0o = fmaf(h0b.w, wo3, a0o);
            a1e = fmaf(h1b.z, we3, a1e); a1o = fmaf(h1b.w, wo3, a1o);
        }
        *(float2*)&G2[tid][0] = make_float2(a0e + a0o, a1e + a1o);
        __syncthreads();
        if (tid < 2 * U) {
            float gi = G2[uu][ur], gj = G2[U + uu][ur];
            float gf = G2[2 * U + uu][ur], go = G2[3 * U + uu][ur];
            c_state = c_state * sig_(gf + 1.0f) + sig_(gi) * tanh_(gj);
            h32[ur][uu] = tanh_(c_state) * sig_(go);
        }
        __syncthreads();
    }
    if (tid < 2 * NC) {
        const int r = tid >> 7, n = tid & (NC - 1);
        float sum = bd[n];
        #pragma unroll 4
        for (int k = 0; k < U; ++k)
            sum = fmaf(h32[r][k], Wd[k * NC + n], sum);
        out[(r0 + r) * NC + n] = sum;
    }
}

extern "C" void kernel_launch(void* const* d_in, const int* in_sizes, int n_in,
                              void* d_out, int out_size, void* d_ws, size_t ws_size,
                              hipStream_t stream) {
    const int*   tokens = (const int*)d_in[0];
    const float* Wx     = (const float*)d_in[1];
    const float* Wh     = (const float*)d_in[2];
    const float* bias   = (const float*)d_in[3];
    const float* Wd     = (const float*)d_in[4];
    const float* bd     = (const float*)d_in[5];
    float*       out    = (float*)d_out;

    if (ws_size >= (size_t)WS_NEED) {
        uint4*  Wp  = (uint4*)((char*)d_ws + WP_OFF);
        float4* Wxp = (float4*)((char*)d_ws + WXP_OFF);
        pack_wh<<<128, 256, 0, stream>>>(Wh, Wp);
        pack_wx<<<128, 256, 0, stream>>>(Wx, bias, Wxp);
        lstm_reg<<<512 / BCR, THREADS, 0, stream>>>(tokens, Wp, Wxp, Wd, bd, out);
    } else {
        uint4* Whb = (uint4*)d_ws;
        pack_kq<<<128, 256, 0, stream>>>(Wh, Whb);
        lstm_stream<<<256, 1024, 0, stream>>>(tokens, Wx, Whb, bias, Wd, bd, out);
    }
}